// Round 1
// baseline (3667.019 us; speedup 1.0000x reference)
//
#include <hip/hip_runtime.h>
#include <hip/hip_bf16.h>

#define T_STEPS 63
#define BATCHSZ 32
#define HID 512
#define VOCAB 32000
#define HSZ (BATCHSZ * HID)          /* floats per h snapshot (16384) */

typedef __bf16 bf16x8 __attribute__((ext_vector_type(8)));
typedef float f32x4 __attribute__((ext_vector_type(4)));

__device__ __forceinline__ unsigned short f2bf(float f) {
    __hip_bfloat16 h = __float2bfloat16(f);
    return *reinterpret_cast<unsigned short*>(&h);
}
__device__ __forceinline__ float sigm(float x) { return 1.0f / (1.0f + __expf(-x)); }

// ---------------------------------------------------------------------------
// device-scope tree barrier: 8 padded leaf counters (64B apart) + 1 root.
// monotonic per-step targets, so no reset race. Requires all 256 blocks
// resident (guaranteed: 128KB LDS -> 1 block/CU, grid == 256 CUs).
// ---------------------------------------------------------------------------
__device__ __forceinline__ void grid_barrier(unsigned* bar, int bid, unsigned step1) {
    __syncthreads();                       // drains vmcnt: all block stores done
    if (threadIdx.x == 0) {
        __threadfence();                   // release: wb L2 so other XCDs see h
        unsigned prev = __hip_atomic_fetch_add(&bar[(bid & 7) * 16], 1u,
                            __ATOMIC_ACQ_REL, __HIP_MEMORY_SCOPE_AGENT);
        if (prev == step1 * 32u - 1u)      // last of this leaf's 32 blocks
            __hip_atomic_fetch_add(&bar[128], 1u,
                __ATOMIC_ACQ_REL, __HIP_MEMORY_SCOPE_AGENT);
        while (__hip_atomic_load(&bar[128], __ATOMIC_ACQUIRE,
                                 __HIP_MEMORY_SCOPE_AGENT) < step1 * 8u)
            __builtin_amdgcn_s_sleep(2);
        __threadfence();                   // acquire: inv L1/L2 before reads
    }
    __syncthreads();
}

// ---------------------------------------------------------------------------
// persistent LSTM: whole 63-step, 2-layer recurrence in one kernel.
// blocks 0..127: layer 0 (j-range blk*4..+4); blocks 128..255: layer 1.
// Layer-1 runs one timestep behind layer-0 (independent within a superstep).
// Thread (sg=tid>>4, rl=tid&15): row_local rl = gate*4+jl, k-segment sg (64
// floats of the 1024-wide comb). Weights live in 16x float4 registers.
// Threads 0..127 own (jl, batch) and keep cell state c in a register.
// ---------------------------------------------------------------------------
__global__ __launch_bounds__(256, 1) void lstm_persistent(
    const float* __restrict__ feat, const int* __restrict__ caps,
    const float* __restrict__ emb,
    const float* __restrict__ Wf, const float* __restrict__ bfp,
    const float* __restrict__ Wi, const float* __restrict__ bip,
    const float* __restrict__ Wc, const float* __restrict__ bcp,
    const float* __restrict__ Wo, const float* __restrict__ bop,
    const float* __restrict__ ihw, const float* __restrict__ ihb,
    const float* __restrict__ icw, const float* __restrict__ icb,
    float* h0buf, float* h1buf, unsigned short* h1all, unsigned* bar)
{
    __shared__ float comb[32 * 1024];     // 128 KB: 32 batch rows x (x|h)
    __shared__ float red[4 * 16 * 36];    // [wave][row][batch(+pad)] partials

    const int tid = threadIdx.x;
    const int bid = blockIdx.x;
    const int l   = bid >> 7;             // layer
    const int blk = bid & 127;
    const int j0  = blk << 2;             // 4 hidden units per block
    const int sg  = tid >> 4;             // k-segment 0..15 (64 floats each)
    const int sgw = sg & 3;               // segment-within-wave (rotation key)
    const int rl  = tid & 15;             // row_local = g*4 + jl
    const int g   = rl >> 2;
    const int jl  = rl & 3;
    const int wv  = tid >> 6;

    // ---- pin weight segment in registers (quarter-rotated by sgw so the 4
    //      broadcast addresses per ds_read land on disjoint bank halves) ----
    const float* Wg = (g == 0) ? Wf : (g == 1) ? Wi : (g == 2) ? Wc : Wo;
    const float4* wrow4 = reinterpret_cast<const float4*>(
        Wg + ((size_t)((l << 9) + j0 + jl) << 10));
    float4 w4[16];
    #pragma unroll
    for (int Q = 0; Q < 4; ++Q) {
        int qi = (Q + sgw) & 3;
        #pragma unroll
        for (int q = 0; q < 4; ++q)
            w4[(Q << 2) + q] = wrow4[(sg << 4) + (qi << 2) + q];
    }

    // ---- init: h0/c0 = feat @ init_{h,c}_w^T + b; c stays in a register ----
    float c_reg = 0.f, bf_r = 0.f, bi_r = 0.f, bc_r = 0.f, bo_r = 0.f;
    if (tid < 128) {
        const int jlc = tid >> 5, bc = tid & 31, j = j0 + jlc;
        bf_r = bfp[(l << 9) + j];
        bi_r = bip[(l << 9) + j];
        bc_r = bcp[(l << 9) + j];
        bo_r = bop[(l << 9) + j];
        const float4* fr = reinterpret_cast<const float4*>(feat + (bc << 9));
        const float4* hr = reinterpret_cast<const float4*>(ihw + ((size_t)j << 9));
        const float4* cr = reinterpret_cast<const float4*>(icw + ((size_t)j << 9));
        float sh = 0.f, sc = 0.f;
        #pragma unroll 4
        for (int k = 0; k < 128; ++k) {
            float4 f = fr[k], hv = hr[k], cv = cr[k];
            sh += f.x * hv.x + f.y * hv.y + f.z * hv.z + f.w * hv.w;
            sc += f.x * cv.x + f.y * cv.y + f.z * cv.z + f.w * cv.w;
        }
        sh += ihb[j];
        c_reg = sc + icb[j];
        float* hb = (l == 0 ? h0buf : h1buf) + HSZ;   // parity-1 buffer
        hb[(bc << 9) + j] = sh;
    }
    grid_barrier(bar, bid, 1u);

    // ---- supersteps: layer0 computes t=s (s<63), layer1 computes t=s-1 ----
    for (int s = 0; s < 64; ++s) {
        const bool active = (l == 0) ? (s < 63) : (s >= 1);
        if (active) {
            const int t = (l == 0) ? s : (s - 1);
            // h0[t-? ] parity: written at superstep p into parity p&1.
            const float4* hx4 = reinterpret_cast<const float4*>(
                h0buf + ((s + 1) & 1) * HSZ);           // h0 from superstep s-1
            const float4* hh4 = (l == 0)
                ? hx4                                    // layer0 recurrent h
                : reinterpret_cast<const float4*>(h1buf + (s & 1) * HSZ);
            const float4* emb4 = reinterpret_cast<const float4*>(emb);

            // stage comb: 8192 float4 granules, 32 per thread (wave-uniform b)
            #pragma unroll 2
            for (int it = 0; it < 32; ++it) {
                int idx = tid + (it << 8);
                int b = idx >> 8, cg = idx & 255;
                float4 v;
                if (cg < 128) {                          // x part
                    if (l == 0) {
                        int tok = caps[(b << 6) + t];
                        v = emb4[(size_t)tok * 128 + cg];
                    } else {
                        v = hx4[(b << 7) + cg];          // x = h0 at same t
                    }
                } else {                                 // recurrent h part
                    v = hh4[(b << 7) + (cg - 128)];
                }
                *reinterpret_cast<float4*>(&comb[idx << 2]) = v;
            }
            __syncthreads();

            // gate pre-activations: each thread dots w4 (64 floats) against
            // 32 batch rows; reduce over the 16 k-segments.
            const float4* cb4 = reinterpret_cast<const float4*>(comb);
            for (int bg = 0; bg < 8; ++bg) {
                float a[4];
                #pragma unroll
                for (int bi2 = 0; bi2 < 4; ++bi2) {
                    const int b = (bg << 2) + bi2;
                    const float4* cbb = cb4 + (b << 8) + (sg << 4);
                    float s0 = 0.f, s1 = 0.f;
                    #pragma unroll
                    for (int Q = 0; Q < 4; ++Q) {
                        const int qi = (Q + sgw) & 3;    // matches w4 rotation
                        #pragma unroll
                        for (int q = 0; q < 4; ++q) {
                            float4 c = cbb[(qi << 2) + q];
                            float4 w = w4[(Q << 2) + q];
                            s0 += w.x * c.x + w.y * c.y;
                            s1 += w.z * c.z + w.w * c.w;
                        }
                    }
                    a[bi2] = s0 + s1;
                }
                #pragma unroll
                for (int bi2 = 0; bi2 < 4; ++bi2) {      // sum 4 in-wave segs
                    a[bi2] += __shfl_down(a[bi2], 32);
                    a[bi2] += __shfl_down(a[bi2], 16);
                }
                if ((tid & 63) < 16)                     // lane = row_local
                    *reinterpret_cast<float4*>(
                        &red[wv * 576 + rl * 36 + (bg << 2)]) =
                        make_float4(a[0], a[1], a[2], a[3]);
            }
            __syncthreads();

            // gate nonlinearities + state update (c in register)
            if (tid < 128) {
                const int jlc = tid >> 5, bc = tid & 31, j = j0 + jlc;
                float s0 = 0.f, s1 = 0.f, s2 = 0.f, s3 = 0.f;
                #pragma unroll
                for (int w = 0; w < 4; ++w) {
                    s0 += red[w * 576 + (0 * 4 + jlc) * 36 + bc];
                    s1 += red[w * 576 + (1 * 4 + jlc) * 36 + bc];
                    s2 += red[w * 576 + (2 * 4 + jlc) * 36 + bc];
                    s3 += red[w * 576 + (3 * 4 + jlc) * 36 + bc];
                }
                float fg = sigm(s0 + bf_r), ig = sigm(s1 + bi_r);
                float ct = tanhf(s2 + bc_r), og = sigm(s3 + bo_r);
                float cn = fg * c_reg + ig * ct;
                c_reg = cn;
                float hn = og * tanhf(cn);
                if (l == 0) {
                    h0buf[(s & 1) * HSZ + (bc << 9) + j] = hn;
                } else {
                    h1buf[((s + 1) & 1) * HSZ + (bc << 9) + j] = hn;
                    h1all[((size_t)t * 32 + bc) * 512 + j] = f2bf(hn);
                }
            }
        }
        grid_barrier(bar, bid, (unsigned)(s + 2));
    }
}

// ---------------------------------------------------------------------------
// projection: C(2016 x 32000) = H(2016 x 512) @ out_w^T + out_b, fp32 out
// with row remap (t*32+b) -> (b*63+t). 128x128 tile, BK=64, 4 waves of 64x64.
// (unchanged from previous verified version)
// ---------------------------------------------------------------------------
__global__ __launch_bounds__(256) void proj_gemm(
    const unsigned short* __restrict__ H, const float* __restrict__ W,
    const float* __restrict__ bias, float* __restrict__ out)
{
    __shared__ unsigned short sA[128 * 72];
    __shared__ unsigned short sB[128 * 72];
    const int tid = threadIdx.x;
    const int bm = blockIdx.x, bn = blockIdx.y;
    const int wave = tid >> 6, lane = tid & 63;
    const int wm = (wave >> 1) << 6, wn = (wave & 1) << 6;
    const int lr = lane & 15, quad = lane >> 4;

    f32x4 acc[4][4];
    #pragma unroll
    for (int i = 0; i < 4; ++i)
        #pragma unroll
        for (int j = 0; j < 4; ++j) acc[i][j] = (f32x4){0.f, 0.f, 0.f, 0.f};

    for (int k0 = 0; k0 < 512; k0 += 64) {
        __syncthreads();
        #pragma unroll
        for (int it = 0; it < 4; ++it) {
            int c = tid + (it << 8);
            int row = c >> 3, col = (c & 7) << 3;
            int gm = (bm << 7) + row;
            uint4 av = make_uint4(0u, 0u, 0u, 0u);
            if (gm < 2016)
                av = *reinterpret_cast<const uint4*>(&H[(size_t)gm * 512 + k0 + col]);
            *reinterpret_cast<uint4*>(&sA[row * 72 + col]) = av;
        }
        #pragma unroll
        for (int it = 0; it < 8; ++it) {
            int c = tid + (it << 8);
            int row = c >> 4, col = (c & 15) << 2;
            int gn = (bn << 7) + row;
            float4 bv = *reinterpret_cast<const float4*>(&W[(size_t)gn * 512 + k0 + col]);
            uint2 p;
            p.x = (unsigned int)f2bf(bv.x) | ((unsigned int)f2bf(bv.y) << 16);
            p.y = (unsigned int)f2bf(bv.z) | ((unsigned int)f2bf(bv.w) << 16);
            *reinterpret_cast<uint2*>(&sB[row * 72 + col]) = p;
        }
        __syncthreads();
        #pragma unroll
        for (int ks = 0; ks < 2; ++ks) {
            bf16x8 af[4], bg[4];
            #pragma unroll
            for (int i = 0; i < 4; ++i)
                af[i] = *reinterpret_cast<const bf16x8*>(
                    &sA[(wm + (i << 4) + lr) * 72 + (ks << 5) + (quad << 3)]);
            #pragma unroll
            for (int i = 0; i < 4; ++i)
                bg[i] = *reinterpret_cast<const bf16x8*>(
                    &sB[(wn + (i << 4) + lr) * 72 + (ks << 5) + (quad << 3)]);
            #pragma unroll
            for (int mi = 0; mi < 4; ++mi)
                #pragma unroll
                for (int ni = 0; ni < 4; ++ni)
                    acc[mi][ni] = __builtin_amdgcn_mfma_f32_16x16x32_bf16(
                        af[mi], bg[ni], acc[mi][ni], 0, 0, 0);
        }
    }

    #pragma unroll
    for (int ni = 0; ni < 4; ++ni) {
        int n = (bn << 7) + wn + (ni << 4) + lr;
        float bv = bias[n];
        #pragma unroll
        for (int mi = 0; mi < 4; ++mi) {
            #pragma unroll
            for (int r = 0; r < 4; ++r) {
                int m = (bm << 7) + wm + (mi << 4) + (quad << 2) + r;
                if (m < 2016) {
                    int b = m & 31, tt = m >> 5;
                    out[((size_t)(b * 63 + tt)) * VOCAB + n] = acc[mi][ni][r] + bv;
                }
            }
        }
    }
}

extern "C" void kernel_launch(void* const* d_in, const int* in_sizes, int n_in,
                              void* d_out, int out_size, void* d_ws, size_t ws_size,
                              hipStream_t stream) {
    const float* feat = (const float*)d_in[0];
    const int*   caps = (const int*)d_in[1];
    const float* emb  = (const float*)d_in[2];
    const float* Wf   = (const float*)d_in[3];
    const float* bfp  = (const float*)d_in[4];
    const float* Wi   = (const float*)d_in[5];
    const float* bip  = (const float*)d_in[6];
    const float* Wc   = (const float*)d_in[7];
    const float* bcp  = (const float*)d_in[8];
    const float* Wo   = (const float*)d_in[9];
    const float* bop  = (const float*)d_in[10];
    const float* Wout = (const float*)d_in[11];
    const float* bout = (const float*)d_in[12];
    const float* ihw  = (const float*)d_in[13];
    const float* ihb  = (const float*)d_in[14];
    const float* icw  = (const float*)d_in[15];
    const float* icb  = (const float*)d_in[16];

    char* ws = (char*)d_ws;
    unsigned* bar        = (unsigned*)ws;                       // 1 KB barrier state
    float* h0buf         = (float*)(ws + 1024);                 // 2 x 32x512 f32
    float* h1buf         = (float*)(ws + 1024 + 131072);        // 2 x 32x512 f32
    unsigned short* h1all = (unsigned short*)(ws + 1024 + 262144); // 63*32*512 bf16

    hipMemsetAsync(ws, 0, 1024, stream);    // reset barrier counters each replay

    lstm_persistent<<<dim3(256), dim3(256), 0, stream>>>(
        feat, caps, emb, Wf, bfp, Wi, bip, Wc, bcp, Wo, bop,
        ihw, ihb, icw, icb, h0buf, h1buf, h1all, bar);

    proj_gemm<<<dim3(16, 250), dim3(256), 0, stream>>>(h1all, Wout, bout,
                                                       (float*)d_out);
}

// Round 2
// 1832.599 us; speedup vs baseline: 2.0010x; 2.0010x over previous
//
#include <hip/hip_runtime.h>
#include <hip/hip_bf16.h>

#define T_STEPS 63
#define BATCHSZ 32
#define HID 512
#define VOCAB 32000
#define HSZ (BATCHSZ * HID)          /* floats per h snapshot (16384) */

typedef __bf16 bf16x8 __attribute__((ext_vector_type(8)));
typedef float f32x4 __attribute__((ext_vector_type(4)));

__device__ __forceinline__ unsigned short f2bf(float f) {
    __hip_bfloat16 h = __float2bfloat16(f);
    return *reinterpret_cast<unsigned short*>(&h);
}
__device__ __forceinline__ float sigm(float x) { return 1.0f / (1.0f + __expf(-x)); }

// ---------------------------------------------------------------------------
// device-coherent accesses: relaxed AGENT atomics compile to sc0/sc1-flagged
// global ops that serialize at the L3 (MALL) coherence point. No L2
// writeback/invalidate instructions are ever issued on this path.
// ---------------------------------------------------------------------------
__device__ __forceinline__ float4 coh16(const float* p) {
    const unsigned long long* q = reinterpret_cast<const unsigned long long*>(p);
    unsigned long long a = __hip_atomic_load(q,     __ATOMIC_RELAXED, __HIP_MEMORY_SCOPE_AGENT);
    unsigned long long b = __hip_atomic_load(q + 1, __ATOMIC_RELAXED, __HIP_MEMORY_SCOPE_AGENT);
    float4 v;
    v.x = __uint_as_float((unsigned)(a & 0xffffffffu));
    v.y = __uint_as_float((unsigned)(a >> 32));
    v.z = __uint_as_float((unsigned)(b & 0xffffffffu));
    v.w = __uint_as_float((unsigned)(b >> 32));
    return v;
}
__device__ __forceinline__ void coh_store(float* p, float v) {
    __hip_atomic_store(p, v, __ATOMIC_RELAXED, __HIP_MEMORY_SCOPE_AGENT);
}

// ---------------------------------------------------------------------------
// grid barrier: 8 leaf counters (64B apart) + root. ALL atomics relaxed,
// polls relaxed + s_sleep, compiler-only fences. Hardware ordering:
// __syncthreads drains vmcnt (all sc1 h-stores ACKed at L3) before thread0's
// arrival add; root increment is data-dependent on leaf result; readers'
// sc1 loads go to L3 and therefore see everything that arrived before the
// counter. Requires all 256 blocks resident (128KB+ LDS -> 1 block/CU).
// ---------------------------------------------------------------------------
__device__ __forceinline__ void grid_barrier(unsigned* bar, int bid, unsigned step) {
    __syncthreads();
    if (threadIdx.x == 0) {
        asm volatile("" ::: "memory");
        unsigned prev = __hip_atomic_fetch_add(&bar[(bid & 7) << 4], 1u,
                            __ATOMIC_RELAXED, __HIP_MEMORY_SCOPE_AGENT);
        if (prev == step * 32u - 1u)
            __hip_atomic_fetch_add(&bar[128], 1u,
                __ATOMIC_RELAXED, __HIP_MEMORY_SCOPE_AGENT);
        while (__hip_atomic_load(&bar[128], __ATOMIC_RELAXED,
                                 __HIP_MEMORY_SCOPE_AGENT) < step * 8u)
            __builtin_amdgcn_s_sleep(4);
        asm volatile("" ::: "memory");
    }
    __syncthreads();
}

// ---------------------------------------------------------------------------
// persistent LSTM. 256 blocks x 512 threads, 1 block/CU (8 waves/CU).
// blocks 0..127: layer 0; 128..255: layer 1 (one step behind, independent).
// Block owns 4 hidden units x 4 gates = 16 rows x 1024 K.
// Thread (rl=tid&7, seg=tid>>3): rows {rl, rl+8}, 16 K-floats (seg) each.
// -> reuse=2: LDS-read cycles == VALU cycles per CU (~4096 each, overlapped).
// Bank rotation qe=(q+(seg>>1))&3 puts the 8 distinct broadcast addresses of
// each ds_read_b128 on all 32 banks (conflict-free).
// ---------------------------------------------------------------------------
__global__ __launch_bounds__(512, 1) void lstm_persistent(
    const float* __restrict__ feat, const int* __restrict__ caps,
    const float* __restrict__ emb,
    const float* __restrict__ Wf, const float* __restrict__ bfp,
    const float* __restrict__ Wi, const float* __restrict__ bip,
    const float* __restrict__ Wc, const float* __restrict__ bcp,
    const float* __restrict__ Wo, const float* __restrict__ bop,
    const float* __restrict__ ihw, const float* __restrict__ ihb,
    const float* __restrict__ icw, const float* __restrict__ icb,
    float* h0buf, float* h1buf, unsigned short* h1all, unsigned* bar)
{
    __shared__ float comb[32 * 1024];     // 128 KB
    __shared__ float red[8 * 16 * 36];    // 18 KB wave partials

    const int tid = threadIdx.x;
    const int bid = blockIdx.x;
    const int l   = bid >> 7;
    const int blk = bid & 127;
    const int j0  = blk << 2;

    const int rl  = tid & 7;              // row-pair id
    const int seg = tid >> 3;             // 0..63 (16 floats each)
    const int rot = (seg >> 1) & 3;
    const int wv  = tid >> 6;
    const int gA  = rl >> 2;              // rows: rl -> gate gA ; rl+8 -> gA+2
    const int jl  = rl & 3;

    // ---- pin weights in VGPRs: 2 rows x 16 floats, rotation baked in ----
    const float* WgA = (gA == 0) ? Wf : Wi;
    const float* WgB = (gA == 0) ? Wc : Wo;
    const float4* rowA4 = reinterpret_cast<const float4*>(
        WgA + ((size_t)((l << 9) + j0 + jl) << 10));
    const float4* rowB4 = reinterpret_cast<const float4*>(
        WgB + ((size_t)((l << 9) + j0 + jl) << 10));
    float4 w4A[4], w4B[4];
    int qe[4];
    #pragma unroll
    for (int q = 0; q < 4; ++q) {
        qe[q] = (q + rot) & 3;
        w4A[q] = rowA4[(seg << 2) + qe[q]];
        w4B[q] = rowB4[(seg << 2) + qe[q]];
    }

    // ---- init: h0/c0 = feat @ init_{h,c}_w^T + b; c stays in register ----
    float c_reg = 0.f, bf_r = 0.f, bi_r = 0.f, bc_r = 0.f, bo_r = 0.f;
    if (tid < 128) {
        const int jlc = tid >> 5, bc = tid & 31, j = j0 + jlc;
        bf_r = bfp[(l << 9) + j];
        bi_r = bip[(l << 9) + j];
        bc_r = bcp[(l << 9) + j];
        bo_r = bop[(l << 9) + j];
        const float4* fr = reinterpret_cast<const float4*>(feat + (bc << 9));
        const float4* hr = reinterpret_cast<const float4*>(ihw + ((size_t)j << 9));
        const float4* cr = reinterpret_cast<const float4*>(icw + ((size_t)j << 9));
        float sh = 0.f, sc = 0.f;
        #pragma unroll 4
        for (int k = 0; k < 128; ++k) {
            float4 f = fr[k], hv = hr[k], cv = cr[k];
            sh += f.x * hv.x + f.y * hv.y + f.z * hv.z + f.w * hv.w;
            sc += f.x * cv.x + f.y * cv.y + f.z * cv.z + f.w * cv.w;
        }
        sh += ihb[j];
        c_reg = sc + icb[j];
        float* hb = (l == 0 ? h0buf : h1buf) + HSZ;   // parity-1 buffer
        coh_store(&hb[(bc << 9) + j], sh);
    }
    grid_barrier(bar, bid, 1u);

    const int cg  = tid & 255;            // staging granule column (constant)
    const int bhi = tid >> 8;

    // ---- supersteps: layer0 computes t=s (s<63), layer1 computes t=s-1 ----
    for (int s = 0; s < 64; ++s) {
        const bool active = (l == 0) ? (s < 63) : (s >= 1);
        if (active) {
            const int t = (l == 0) ? s : (s - 1);
            const float* h0p = h0buf + (((s + 1) & 1) ? HSZ : 0);
            const float* h1p = h1buf + ((s & 1) ? HSZ : 0);

            // stage comb: each thread owns one 16B column across 32 batches
            if (cg < 128) {                           // x half
                if (l == 0) {
                    #pragma unroll
                    for (int it = 0; it < 16; ++it) {
                        int b = (it << 1) + bhi;
                        int tok = caps[(b << 6) + t];
                        float4 v = *reinterpret_cast<const float4*>(
                            emb + ((size_t)tok << 9) + (cg << 2));
                        *reinterpret_cast<float4*>(&comb[((b << 8) + cg) << 2]) = v;
                    }
                } else {
                    #pragma unroll
                    for (int it = 0; it < 16; ++it) {
                        int b = (it << 1) + bhi;
                        float4 v = coh16(h0p + (b << 9) + (cg << 2));
                        *reinterpret_cast<float4*>(&comb[((b << 8) + cg) << 2]) = v;
                    }
                }
            } else {                                  // recurrent-h half
                const float* hp = (l == 0) ? h0p : h1p;
                const int ch = cg - 128;
                #pragma unroll
                for (int it = 0; it < 16; ++it) {
                    int b = (it << 1) + bhi;
                    float4 v = coh16(hp + (b << 9) + (ch << 2));
                    *reinterpret_cast<float4*>(&comb[((b << 8) + cg) << 2]) = v;
                }
            }
            __syncthreads();

            // gate pre-activations
            const float4* cb4 = reinterpret_cast<const float4*>(comb);
            const float4* Aq0 = cb4 + (seg << 2) + qe[0];
            const float4* Aq1 = cb4 + (seg << 2) + qe[1];
            const float4* Aq2 = cb4 + (seg << 2) + qe[2];
            const float4* Aq3 = cb4 + (seg << 2) + qe[3];
            for (int bg = 0; bg < 8; ++bg) {
                float aA[4], aB[4];
                #pragma unroll
                for (int bi2 = 0; bi2 < 4; ++bi2) {
                    const int b = (bg << 2) + bi2;
                    float4 c0 = Aq0[b << 8], c1 = Aq1[b << 8];
                    float4 c2 = Aq2[b << 8], c3 = Aq3[b << 8];
                    aA[bi2] = w4A[0].x*c0.x + w4A[0].y*c0.y + w4A[0].z*c0.z + w4A[0].w*c0.w
                            + w4A[1].x*c1.x + w4A[1].y*c1.y + w4A[1].z*c1.z + w4A[1].w*c1.w
                            + w4A[2].x*c2.x + w4A[2].y*c2.y + w4A[2].z*c2.z + w4A[2].w*c2.w
                            + w4A[3].x*c3.x + w4A[3].y*c3.y + w4A[3].z*c3.z + w4A[3].w*c3.w;
                    aB[bi2] = w4B[0].x*c0.x + w4B[0].y*c0.y + w4B[0].z*c0.z + w4B[0].w*c0.w
                            + w4B[1].x*c1.x + w4B[1].y*c1.y + w4B[1].z*c1.z + w4B[1].w*c1.w
                            + w4B[2].x*c2.x + w4B[2].y*c2.y + w4B[2].z*c2.z + w4B[2].w*c2.w
                            + w4B[3].x*c3.x + w4B[3].y*c3.y + w4B[3].z*c3.z + w4B[3].w*c3.w;
                }
                #pragma unroll
                for (int bi2 = 0; bi2 < 4; ++bi2) {   // reduce 8 in-wave segs
                    aA[bi2] += __shfl_down(aA[bi2], 32, 64);
                    aB[bi2] += __shfl_down(aB[bi2], 32, 64);
                    aA[bi2] += __shfl_down(aA[bi2], 16, 64);
                    aB[bi2] += __shfl_down(aB[bi2], 16, 64);
                    aA[bi2] += __shfl_down(aA[bi2], 8, 64);
                    aB[bi2] += __shfl_down(aB[bi2], 8, 64);
                }
                if ((tid & 63) < 8) {
                    *reinterpret_cast<float4*>(
                        &red[((wv << 4) + rl) * 36 + (bg << 2)]) =
                        make_float4(aA[0], aA[1], aA[2], aA[3]);
                    *reinterpret_cast<float4*>(
                        &red[((wv << 4) + rl + 8) * 36 + (bg << 2)]) =
                        make_float4(aB[0], aB[1], aB[2], aB[3]);
                }
            }
            __syncthreads();

            // gate nonlinearities + state update (c in register)
            if (tid < 128) {
                const int jlc = tid >> 5, bc = tid & 31, j = j0 + jlc;
                float s0 = 0.f, s1 = 0.f, s2 = 0.f, s3 = 0.f;
                #pragma unroll
                for (int w = 0; w < 8; ++w) {
                    s0 += red[((w << 4) + 0 + jlc) * 36 + bc];
                    s1 += red[((w << 4) + 4 + jlc) * 36 + bc];
                    s2 += red[((w << 4) + 8 + jlc) * 36 + bc];
                    s3 += red[((w << 4) + 12 + jlc) * 36 + bc];
                }
                float fg = sigm(s0 + bf_r), ig = sigm(s1 + bi_r);
                float ct = tanhf(s2 + bc_r), og = sigm(s3 + bo_r);
                float cn = fg * c_reg + ig * ct;
                c_reg = cn;
                float hn = og * tanhf(cn);
                if (l == 0) {
                    coh_store(&h0buf[(s & 1) * HSZ + (bc << 9) + j], hn);
                } else {
                    coh_store(&h1buf[((s + 1) & 1) * HSZ + (bc << 9) + j], hn);
                    h1all[((size_t)t * BATCHSZ + bc) * 512 + j] = f2bf(hn);
                }
            }
        }
        if (s < 63) grid_barrier(bar, bid, (unsigned)(s + 2));
    }
}

// ---------------------------------------------------------------------------
// projection: C(2016 x 32000) = H(2016 x 512) @ out_w^T + out_b, fp32 out
// with row remap (t*32+b) -> (b*63+t). 128x128 tile, BK=64, 4 waves of 64x64.
// (unchanged from verified version)
// ---------------------------------------------------------------------------
__global__ __launch_bounds__(256) void proj_gemm(
    const unsigned short* __restrict__ H, const float* __restrict__ W,
    const float* __restrict__ bias, float* __restrict__ out)
{
    __shared__ unsigned short sA[128 * 72];
    __shared__ unsigned short sB[128 * 72];
    const int tid = threadIdx.x;
    const int bm = blockIdx.x, bn = blockIdx.y;
    const int wave = tid >> 6, lane = tid & 63;
    const int wm = (wave >> 1) << 6, wn = (wave & 1) << 6;
    const int lr = lane & 15, quad = lane >> 4;

    f32x4 acc[4][4];
    #pragma unroll
    for (int i = 0; i < 4; ++i)
        #pragma unroll
        for (int j = 0; j < 4; ++j) acc[i][j] = (f32x4){0.f, 0.f, 0.f, 0.f};

    for (int k0 = 0; k0 < 512; k0 += 64) {
        __syncthreads();
        #pragma unroll
        for (int it = 0; it < 4; ++it) {
            int c = tid + (it << 8);
            int row = c >> 3, col = (c & 7) << 3;
            int gm = (bm << 7) + row;
            uint4 av = make_uint4(0u, 0u, 0u, 0u);
            if (gm < 2016)
                av = *reinterpret_cast<const uint4*>(&H[(size_t)gm * 512 + k0 + col]);
            *reinterpret_cast<uint4*>(&sA[row * 72 + col]) = av;
        }
        #pragma unroll
        for (int it = 0; it < 8; ++it) {
            int c = tid + (it << 8);
            int row = c >> 4, col = (c & 15) << 2;
            int gn = (bn << 7) + row;
            float4 bv = *reinterpret_cast<const float4*>(&W[(size_t)gn * 512 + k0 + col]);
            uint2 p;
            p.x = (unsigned int)f2bf(bv.x) | ((unsigned int)f2bf(bv.y) << 16);
            p.y = (unsigned int)f2bf(bv.z) | ((unsigned int)f2bf(bv.w) << 16);
            *reinterpret_cast<uint2*>(&sB[row * 72 + col]) = p;
        }
        __syncthreads();
        #pragma unroll
        for (int ks = 0; ks < 2; ++ks) {
            bf16x8 af[4], bg[4];
            #pragma unroll
            for (int i = 0; i < 4; ++i)
                af[i] = *reinterpret_cast<const bf16x8*>(
                    &sA[(wm + (i << 4) + lr) * 72 + (ks << 5) + (quad << 3)]);
            #pragma unroll
            for (int i = 0; i < 4; ++i)
                bg[i] = *reinterpret_cast<const bf16x8*>(
                    &sB[(wn + (i << 4) + lr) * 72 + (ks << 5) + (quad << 3)]);
            #pragma unroll
            for (int mi = 0; mi < 4; ++mi)
                #pragma unroll
                for (int ni = 0; ni < 4; ++ni)
                    acc[mi][ni] = __builtin_amdgcn_mfma_f32_16x16x32_bf16(
                        af[mi], bg[ni], acc[mi][ni], 0, 0, 0);
        }
    }

    #pragma unroll
    for (int ni = 0; ni < 4; ++ni) {
        int n = (bn << 7) + wn + (ni << 4) + lr;
        float bv = bias[n];
        #pragma unroll
        for (int mi = 0; mi < 4; ++mi) {
            #pragma unroll
            for (int r = 0; r < 4; ++r) {
                int m = (bm << 7) + wm + (mi << 4) + (quad << 2) + r;
                if (m < 2016) {
                    int b = m & 31, tt = m >> 5;
                    out[((size_t)(b * 63 + tt)) * VOCAB + n] = acc[mi][ni][r] + bv;
                }
            }
        }
    }
}

extern "C" void kernel_launch(void* const* d_in, const int* in_sizes, int n_in,
                              void* d_out, int out_size, void* d_ws, size_t ws_size,
                              hipStream_t stream) {
    const float* feat = (const float*)d_in[0];
    const int*   caps = (const int*)d_in[1];
    const float* emb  = (const float*)d_in[2];
    const float* Wf   = (const float*)d_in[3];
    const float* bfp  = (const float*)d_in[4];
    const float* Wi   = (const float*)d_in[5];
    const float* bip  = (const float*)d_in[6];
    const float* Wc   = (const float*)d_in[7];
    const float* bcp  = (const float*)d_in[8];
    const float* Wo   = (const float*)d_in[9];
    const float* bop  = (const float*)d_in[10];
    const float* Wout = (const float*)d_in[11];
    const float* bout = (const float*)d_in[12];
    const float* ihw  = (const float*)d_in[13];
    const float* ihb  = (const float*)d_in[14];
    const float* icw  = (const float*)d_in[15];
    const float* icb  = (const float*)d_in[16];

    char* ws = (char*)d_ws;
    unsigned* bar         = (unsigned*)ws;                          // 1 KB
    float* h0buf          = (float*)(ws + 1024);                    // 2 x 64 KB
    float* h1buf          = (float*)(ws + 1024 + 131072);           // 2 x 64 KB
    unsigned short* h1all = (unsigned short*)(ws + 1024 + 262144);  // ~2 MB

    hipMemsetAsync(ws, 0, 1024, stream);    // reset barrier counters per replay

    lstm_persistent<<<dim3(256), dim3(512), 0, stream>>>(
        feat, caps, emb, Wf, bfp, Wi, bip, Wc, bcp, Wo, bop,
        ihw, ihb, icw, icb, h0buf, h1buf, h1all, bar);

    proj_gemm<<<dim3(16, 250), dim3(256), 0, stream>>>(h1all, Wout, bout,
                                                       (float*)d_out);
}

// Round 3
// 1596.081 us; speedup vs baseline: 2.2975x; 1.1482x over previous
//
#include <hip/hip_runtime.h>
#include <hip/hip_bf16.h>

#define T_STEPS 63
#define BATCHSZ 32
#define HID 512
#define VOCAB 32000
#define HSZ (BATCHSZ * HID)          /* floats per h snapshot (16384) */

typedef __bf16 bf16x8 __attribute__((ext_vector_type(8)));
typedef float f32x4 __attribute__((ext_vector_type(4)));

__device__ __forceinline__ unsigned short f2bf(float f) {
    __hip_bfloat16 h = __float2bfloat16(f);
    return *reinterpret_cast<unsigned short*>(&h);
}
__device__ __forceinline__ float sigm(float x) { return 1.0f / (1.0f + __expf(-x)); }

// device-coherent accesses (sc0/sc1 at the L3 coherence point; no cache
// maintenance instructions on this path). Same mechanism verified in r2.
__device__ __forceinline__ float4 coh16(const float* p) {
    const unsigned long long* q = reinterpret_cast<const unsigned long long*>(p);
    unsigned long long a = __hip_atomic_load(q,     __ATOMIC_RELAXED, __HIP_MEMORY_SCOPE_AGENT);
    unsigned long long b = __hip_atomic_load(q + 1, __ATOMIC_RELAXED, __HIP_MEMORY_SCOPE_AGENT);
    float4 v;
    v.x = __uint_as_float((unsigned)(a & 0xffffffffu));
    v.y = __uint_as_float((unsigned)(a >> 32));
    v.z = __uint_as_float((unsigned)(b & 0xffffffffu));
    v.w = __uint_as_float((unsigned)(b >> 32));
    return v;
}
__device__ __forceinline__ void coh_store(float* p, float v) {
    __hip_atomic_store(p, v, __ATOMIC_RELAXED, __HIP_MEMORY_SCOPE_AGENT);
}

// ---------------------------------------------------------------------------
// grid barrier, ZERO atomic RMWs: block bid stores monotonic step into its
// own flag (no contention); wave0 polls all 256 flags with 4 coalesced
// relaxed loads + ballot. Ordering: __syncthreads drains vmcnt (all sc1
// h-stores ACKed at L3) before the flag store; readers' sc1 loads hit L3
// after seeing flag>=step. Requires all 256 blocks resident (86KB LDS ->
// 1 block/CU, grid == 256 CUs).
// ---------------------------------------------------------------------------
__device__ __forceinline__ void grid_barrier(unsigned* bar, int bid, unsigned step) {
    __syncthreads();
    const int tid = threadIdx.x;
    if (tid == 0)
        __hip_atomic_store(&bar[bid], step, __ATOMIC_RELAXED, __HIP_MEMORY_SCOPE_AGENT);
    if (tid < 64) {
        const unsigned* f = bar + tid;
        for (;;) {
            unsigned a = __hip_atomic_load(f,       __ATOMIC_RELAXED, __HIP_MEMORY_SCOPE_AGENT);
            unsigned b = __hip_atomic_load(f + 64,  __ATOMIC_RELAXED, __HIP_MEMORY_SCOPE_AGENT);
            unsigned c = __hip_atomic_load(f + 128, __ATOMIC_RELAXED, __HIP_MEMORY_SCOPE_AGENT);
            unsigned d = __hip_atomic_load(f + 192, __ATOMIC_RELAXED, __HIP_MEMORY_SCOPE_AGENT);
            if (__all(a >= step && b >= step && c >= step && d >= step)) break;
            __builtin_amdgcn_s_sleep(1);
        }
        asm volatile("" ::: "memory");
    }
    __syncthreads();
}

// ---------------------------------------------------------------------------
// persistent LSTM. 256 blocks x 512 threads, 1 block/CU.
// bid = layer(2) x jblk(64) x bhalf(2): block owns 8 hidden units x 4 gates
// = 32 weight rows x 1024 K, for 16 of the 32 batch rows.
// Thread: rl=tid&15 -> rows {rl, rl+16}; seg = wave*4 + ((tid>>4)&3) (32
// floats of K). In-wave reduce = 2 shfl levels (4 segs/wave); cross-wave
// via red[]. comb is XOR-swizzled (slot = g ^ ((g>>3)&7)) so the broadcast
// ds_read_b128 (16-lane broadcast x 4 distinct granules) is conflict-free.
// Staging is chunk-pipelined (4 batches/chunk): loads for chunk c+1 issue
// before compute of chunk c. Layer-0's emb x-half is register-prefetched
// one step ahead (t+1 gather known in advance).
// ---------------------------------------------------------------------------
__global__ __launch_bounds__(512, 1) void lstm_persistent(
    const float* __restrict__ feat, const int* __restrict__ caps,
    const float* __restrict__ emb,
    const float* __restrict__ Wf, const float* __restrict__ bfp,
    const float* __restrict__ Wi, const float* __restrict__ bip,
    const float* __restrict__ Wc, const float* __restrict__ bcp,
    const float* __restrict__ Wo, const float* __restrict__ bop,
    const float* __restrict__ ihw, const float* __restrict__ ihb,
    const float* __restrict__ icw, const float* __restrict__ icb,
    float* h0buf, float* h1buf, unsigned short* h1all, unsigned* bar)
{
    __shared__ float comb[16 * 1024];     // 64 KB, swizzled granules
    __shared__ float red[8 * 32 * 20];    // 20 KB wave partials

    const int tid = threadIdx.x;
    const int bid = blockIdx.x;
    const int l   = bid >> 7;
    const int sub = bid & 127;
    const int j0  = (sub >> 1) << 3;      // 8 units
    const int b0  = (sub & 1) << 4;       // 16 batches

    const int wv  = tid >> 6;
    const int seg = (wv << 2) | ((tid >> 4) & 3);   // 0..31, K_seg = 32 floats
    const int rl  = tid & 15;
    const int g   = rl >> 3;              // 0: rows f/c   1: rows i/o
    const int u   = rl & 7;

    const int cg   = tid & 255;           // staging granule column 0..255
    const int bhi  = tid >> 8;            // batch parity for staging
    const int slotW = cg ^ ((cg >> 3) & 7);
    const int chOff = (cg < 128) ? cg : (cg - 128);

    float4* comb4 = reinterpret_cast<float4*>(comb);
    const float4* emb4 = reinterpret_cast<const float4*>(emb);

    // ---- pin weights: 2 rows x 32 floats (granules seg*8+q, straight) ----
    const float* WgA = (g == 0) ? Wf : Wi;
    const float* WgB = (g == 0) ? Wc : Wo;
    const float4* rowA4 = reinterpret_cast<const float4*>(
        WgA + ((size_t)((l << 9) + j0 + u) << 10));
    const float4* rowB4 = reinterpret_cast<const float4*>(
        WgB + ((size_t)((l << 9) + j0 + u) << 10));
    float4 w4A[8], w4B[8];
    #pragma unroll
    for (int q = 0; q < 8; ++q) {
        w4A[q] = rowA4[(seg << 3) + q];
        w4B[q] = rowB4[(seg << 3) + q];
    }

    // ---- init: h0/c0 = feat @ init_{h,c}_w^T + b; c stays in register ----
    float c_reg = 0.f, bf_r = 0.f, bi_r = 0.f, bc_r = 0.f, bo_r = 0.f;
    if (tid < 128) {
        const int uu = tid >> 4, bc = tid & 15;
        const int j = j0 + uu, b = b0 + bc;
        bf_r = bfp[(l << 9) + j];
        bi_r = bip[(l << 9) + j];
        bc_r = bcp[(l << 9) + j];
        bo_r = bop[(l << 9) + j];
        const float4* fr = reinterpret_cast<const float4*>(feat + ((size_t)b << 9));
        const float4* hr = reinterpret_cast<const float4*>(ihw + ((size_t)j << 9));
        const float4* cr = reinterpret_cast<const float4*>(icw + ((size_t)j << 9));
        float sh = 0.f, sc = 0.f;
        #pragma unroll 4
        for (int k = 0; k < 128; ++k) {
            float4 f = fr[k], hv = hr[k], cv = cr[k];
            sh += f.x * hv.x + f.y * hv.y + f.z * hv.z + f.w * hv.w;
            sc += f.x * cv.x + f.y * cv.y + f.z * cv.z + f.w * cv.w;
        }
        sh += ihb[j];
        c_reg = sc + icb[j];
        float* hb = (l == 0 ? h0buf : h1buf) + HSZ;   // parity-1 buffer
        coh_store(&hb[((size_t)b << 9) + j], sh);
    }

    // ---- initial emb prefetch (t = 0) for layer-0 x-half ----
    float4 pf[8];
    if (l == 0 && cg < 128) {
        #pragma unroll
        for (int k = 0; k < 8; ++k) {
            int b = b0 + (k << 1) + bhi;
            int tok = caps[b << 6];
            pf[k] = emb4[(size_t)tok * 128 + cg];
        }
    }

    grid_barrier(bar, bid, 1u);

    // ---- supersteps: layer0 computes t=s (s<63), layer1 computes t=s-1 ----
    for (int s = 0; s < 64; ++s) {
        const bool active = (l == 0) ? (s < 63) : (s >= 1);
        if (active) {
            const int t = (l == 0) ? s : (s - 1);
            const float* h0p = h0buf + (((s + 1) & 1) ? HSZ : 0);
            const float* h1p = h1buf + ((s & 1) ? HSZ : 0);
            const bool fromPf = (l == 0 && cg < 128);
            const float* src = (l == 0) ? h0p : ((cg < 128) ? h0p : h1p);

            // prologue: stage chunk 0 (local batches 0..3)
            {
                float4 L0, L1;
                if (!fromPf) {
                    L0 = coh16(src + ((size_t)(b0 + bhi)     << 9) + (chOff << 2));
                    L1 = coh16(src + ((size_t)(b0 + 2 + bhi) << 9) + (chOff << 2));
                }
                if (fromPf) {
                    comb4[(bhi)     * 256 + slotW] = pf[0];
                    comb4[(2 + bhi) * 256 + slotW] = pf[1];
                } else {
                    comb4[(bhi)     * 256 + slotW] = L0;
                    comb4[(2 + bhi) * 256 + slotW] = L1;
                }
            }
            __syncthreads();

            #pragma unroll
            for (int c = 0; c < 4; ++c) {
                // issue next chunk's coherent loads (latency hides under dot)
                float4 L0, L1;
                if (c < 3 && !fromPf) {
                    L0 = coh16(src + ((size_t)(b0 + 4*(c+1) + bhi)     << 9) + (chOff << 2));
                    L1 = coh16(src + ((size_t)(b0 + 4*(c+1) + 2 + bhi) << 9) + (chOff << 2));
                }
                // compute chunk c (local batches 4c..4c+3)
                float aA[4], aB[4];
                #pragma unroll
                for (int bi2 = 0; bi2 < 4; ++bi2) {
                    const float4* cb = comb4 + (4*c + bi2) * 256;
                    float sA0 = 0.f, sA1 = 0.f, sB0 = 0.f, sB1 = 0.f;
                    #pragma unroll
                    for (int q = 0; q < 8; ++q) {
                        float4 cc = cb[(seg << 3) | (q ^ (seg & 7))];
                        sA0 += w4A[q].x*cc.x + w4A[q].y*cc.y;
                        sA1 += w4A[q].z*cc.z + w4A[q].w*cc.w;
                        sB0 += w4B[q].x*cc.x + w4B[q].y*cc.y;
                        sB1 += w4B[q].z*cc.z + w4B[q].w*cc.w;
                    }
                    aA[bi2] = sA0 + sA1;
                    aB[bi2] = sB0 + sB1;
                }
                #pragma unroll
                for (int bi2 = 0; bi2 < 4; ++bi2) {   // reduce 4 in-wave segs
                    aA[bi2] += __shfl_down(aA[bi2], 16);
                    aB[bi2] += __shfl_down(aB[bi2], 16);
                    aA[bi2] += __shfl_down(aA[bi2], 32);
                    aB[bi2] += __shfl_down(aB[bi2], 32);
                }
                if ((tid & 63) < 16) {
                    *reinterpret_cast<float4*>(
                        &red[((wv << 5) + rl) * 20 + (c << 2)]) =
                        make_float4(aA[0], aA[1], aA[2], aA[3]);
                    *reinterpret_cast<float4*>(
                        &red[((wv << 5) + rl + 16) * 20 + (c << 2)]) =
                        make_float4(aB[0], aB[1], aB[2], aB[3]);
                }
                // publish next chunk
                if (c < 3) {
                    if (fromPf) {
                        comb4[(4*(c+1) + bhi)     * 256 + slotW] = pf[2*(c+1)];
                        comb4[(4*(c+1) + 2 + bhi) * 256 + slotW] = pf[2*(c+1) + 1];
                    } else {
                        comb4[(4*(c+1) + bhi)     * 256 + slotW] = L0;
                        comb4[(4*(c+1) + 2 + bhi) * 256 + slotW] = L1;
                    }
                }
                __syncthreads();
            }

            // prefetch next step's emb gather (layer 0 only)
            if (l == 0 && cg < 128 && s < 62) {
                #pragma unroll
                for (int k = 0; k < 8; ++k) {
                    int b = b0 + (k << 1) + bhi;
                    int tok = caps[(b << 6) + s + 1];
                    pf[k] = emb4[(size_t)tok * 128 + cg];
                }
            }

            // gate nonlinearities + state update (c in register)
            if (tid < 128) {
                const int uu = tid >> 4, bc = tid & 15;
                const int j = j0 + uu, b = b0 + bc;
                float s0 = 0.f, s1 = 0.f, s2 = 0.f, s3 = 0.f;
                #pragma unroll
                for (int w = 0; w < 8; ++w) {
                    s0 += red[((w << 5) + uu)      * 20 + bc];   // rows 0..7  : f
                    s1 += red[((w << 5) + 8 + uu)  * 20 + bc];   // rows 8..15 : i
                    s2 += red[((w << 5) + 16 + uu) * 20 + bc];   // rows 16..23: c
                    s3 += red[((w << 5) + 24 + uu) * 20 + bc];   // rows 24..31: o
                }
                float fg = sigm(s0 + bf_r), ig = sigm(s1 + bi_r);
                float ct = tanhf(s2 + bc_r), og = sigm(s3 + bo_r);
                float cn = fg * c_reg + ig * ct;
                c_reg = cn;
                float hn = og * tanhf(cn);
                if (l == 0) {
                    coh_store(&h0buf[(s & 1) * HSZ + ((size_t)b << 9) + j], hn);
                } else {
                    coh_store(&h1buf[((s + 1) & 1) * HSZ + ((size_t)b << 9) + j], hn);
                    // M-order = b*63+t so proj_gemm reads/writes sequential rows
                    h1all[((size_t)b * 63 + t) * 512 + j] = f2bf(hn);
                }
            }
        }
        if (s < 63) grid_barrier(bar, bid, (unsigned)(s + 2));
    }
}

// ---------------------------------------------------------------------------
// projection: C(2016 x 32000) = H(2016 x 512) @ out_w^T + out_b, fp32 out.
// H rows already in output order (b*63+t) -> fully sequential row writes.
// 128x128 tile, BK=64, 4 waves of 64x64.
// ---------------------------------------------------------------------------
__global__ __launch_bounds__(256) void proj_gemm(
    const unsigned short* __restrict__ H, const float* __restrict__ W,
    const float* __restrict__ bias, float* __restrict__ out)
{
    __shared__ unsigned short sA[128 * 72];
    __shared__ unsigned short sB[128 * 72];
    const int tid = threadIdx.x;
    const int bm = blockIdx.x, bn = blockIdx.y;
    const int wave = tid >> 6, lane = tid & 63;
    const int wm = (wave >> 1) << 6, wn = (wave & 1) << 6;
    const int lr = lane & 15, quad = lane >> 4;

    f32x4 acc[4][4];
    #pragma unroll
    for (int i = 0; i < 4; ++i)
        #pragma unroll
        for (int j = 0; j < 4; ++j) acc[i][j] = (f32x4){0.f, 0.f, 0.f, 0.f};

    for (int k0 = 0; k0 < 512; k0 += 64) {
        __syncthreads();
        #pragma unroll
        for (int it = 0; it < 4; ++it) {
            int c = tid + (it << 8);
            int row = c >> 3, col = (c & 7) << 3;
            int gm = (bm << 7) + row;
            uint4 av = make_uint4(0u, 0u, 0u, 0u);
            if (gm < 2016)
                av = *reinterpret_cast<const uint4*>(&H[(size_t)gm * 512 + k0 + col]);
            *reinterpret_cast<uint4*>(&sA[row * 72 + col]) = av;
        }
        #pragma unroll
        for (int it = 0; it < 8; ++it) {
            int c = tid + (it << 8);
            int row = c >> 4, col = (c & 15) << 2;
            int gn = (bn << 7) + row;
            float4 bv = *reinterpret_cast<const float4*>(&W[(size_t)gn * 512 + k0 + col]);
            uint2 p;
            p.x = (unsigned int)f2bf(bv.x) | ((unsigned int)f2bf(bv.y) << 16);
            p.y = (unsigned int)f2bf(bv.z) | ((unsigned int)f2bf(bv.w) << 16);
            *reinterpret_cast<uint2*>(&sB[row * 72 + col]) = p;
        }
        __syncthreads();
        #pragma unroll
        for (int ks = 0; ks < 2; ++ks) {
            bf16x8 af[4], bg[4];
            #pragma unroll
            for (int i = 0; i < 4; ++i)
                af[i] = *reinterpret_cast<const bf16x8*>(
                    &sA[(wm + (i << 4) + lr) * 72 + (ks << 5) + (quad << 3)]);
            #pragma unroll
            for (int i = 0; i < 4; ++i)
                bg[i] = *reinterpret_cast<const bf16x8*>(
                    &sB[(wn + (i << 4) + lr) * 72 + (ks << 5) + (quad << 3)]);
            #pragma unroll
            for (int mi = 0; mi < 4; ++mi)
                #pragma unroll
                for (int ni = 0; ni < 4; ++ni)
                    acc[mi][ni] = __builtin_amdgcn_mfma_f32_16x16x32_bf16(
                        af[mi], bg[ni], acc[mi][ni], 0, 0, 0);
        }
    }

    #pragma unroll
    for (int ni = 0; ni < 4; ++ni) {
        int n = (bn << 7) + wn + (ni << 4) + lr;
        float bv = bias[n];
        #pragma unroll
        for (int mi = 0; mi < 4; ++mi) {
            #pragma unroll
            for (int r = 0; r < 4; ++r) {
                int m = (bm << 7) + wm + (mi << 4) + (quad << 2) + r;
                if (m < 2016)
                    out[(size_t)m * VOCAB + n] = acc[mi][ni][r] + bv;
            }
        }
    }
}

extern "C" void kernel_launch(void* const* d_in, const int* in_sizes, int n_in,
                              void* d_out, int out_size, void* d_ws, size_t ws_size,
                              hipStream_t stream) {
    const float* feat = (const float*)d_in[0];
    const int*   caps = (const int*)d_in[1];
    const float* emb  = (const float*)d_in[2];
    const float* Wf   = (const float*)d_in[3];
    const float* bfp  = (const float*)d_in[4];
    const float* Wi   = (const float*)d_in[5];
    const float* bip  = (const float*)d_in[6];
    const float* Wc   = (const float*)d_in[7];
    const float* bcp  = (const float*)d_in[8];
    const float* Wo   = (const float*)d_in[9];
    const float* bop  = (const float*)d_in[10];
    const float* Wout = (const float*)d_in[11];
    const float* bout = (const float*)d_in[12];
    const float* ihw  = (const float*)d_in[13];
    const float* ihb  = (const float*)d_in[14];
    const float* icw  = (const float*)d_in[15];
    const float* icb  = (const float*)d_in[16];

    char* ws = (char*)d_ws;
    unsigned* bar         = (unsigned*)ws;                          // 1 KB flags
    float* h0buf          = (float*)(ws + 1024);                    // 2 x 64 KB
    float* h1buf          = (float*)(ws + 1024 + 131072);           // 2 x 64 KB
    unsigned short* h1all = (unsigned short*)(ws + 1024 + 262144);  // ~2 MB

    hipMemsetAsync(ws, 0, 1024, stream);    // reset flags per replay

    lstm_persistent<<<dim3(256), dim3(512), 0, stream>>>(
        feat, caps, emb, Wf, bfp, Wi, bip, Wc, bcp, Wo, bop,
        ihw, ihb, icw, icb, h0buf, h1buf, h1all, bar);

    proj_gemm<<<dim3(16, 250), dim3(256), 0, stream>>>(h1all, Wout, bout,
                                                       (float*)d_out);
}